// Round 14
// baseline (36.438 us; speedup 1.0000x reference)
//
#include <hip/hip_runtime.h>
#include <hip/hip_bf16.h>
#include <hip/hip_fp16.h>

typedef __attribute__((ext_vector_type(8))) short bf16x8;
typedef __attribute__((ext_vector_type(4))) float f32x4;
typedef __attribute__((ext_vector_type(4))) int   i32x4;

#define O_TOTAL 8192
#define I_TOTAL 8192
#define ROW_I32 4096       // int32 per weight row
#define NBLOCKS 256        // 32-wide k-blocks per row
#define MSTEPS  8          // mega-steps: 1024 k (2 KB/row) each

typedef __attribute__((address_space(1))) const void GASV;
typedef __attribute__((address_space(3))) void LASV;

static __device__ __forceinline__ short f2bf(float f) {
    union { __hip_bfloat16 b; short s; } u;
    u.b = __float2bfloat16(f);
    return u.s;
}

static __device__ __forceinline__ float bf2f(unsigned short s) {
    union { unsigned int u; float f; } v;
    v.u = ((unsigned int)s) << 16;
    return v.f;
}

static __device__ __forceinline__ int sniff_fmt(const void* wn) {
    const unsigned int* w32 = (const unsigned int*)wn;
    int cntLo = 0, cntHi = 0;
    #pragma unroll
    for (int i = 0; i < 16; ++i) {
        unsigned int ww = w32[i];
        unsigned int lo = ww & 0xFFFFu, hi = ww >> 16;
        if (lo >= 0x3980u && lo < 0x3F80u) cntLo++;
        if (hi >= 0x3C00u) cntHi++;
    }
    return (cntLo >= 12) ? 1 : (cntHi >= 12 ? 0 : 2); // 0=f32 1=bf16 2=f16
}

static __device__ __forceinline__ float decode_norm(const void* wn, int idx, int fmt) {
    if (fmt == 0) return ((const float*)wn)[idx];
    if (fmt == 1) return bf2f(((const unsigned short*)wn)[idx]);
    return __half2float(((const __half*)wn)[idx]);
}

// ---- kernel 0: x fp32 -> bf16 bits ----
__global__ __launch_bounds__(256)
void xcvt_kernel(const float* __restrict__ x, short* __restrict__ xb)
{
    const int i = (blockIdx.x * 256 + threadIdx.x) * 4;
    f32x4 v = *(const f32x4*)(x + i);
    union { short s[4]; long long q; } p;
    p.s[0] = f2bf(v[0]); p.s[1] = f2bf(v[1]); p.s[2] = f2bf(v[2]); p.s[3] = f2bf(v[3]);
    *(long long*)(xb + i) = p.q;
}

// ---- kernel 1: mega-burst kernel. 512 blocks x 8 waves; 8 mega-steps of
//      1024 k; each row fetched in 2 KB contiguous runs (sequential stream) ----
__global__ __launch_bounds__(512, 4)
void gemm_mb(const short* __restrict__ xb,
             const int* __restrict__ wq,
             const void* __restrict__ wn,
             const float* __restrict__ bias,
             float* __restrict__ out)
{
    const int tid  = threadIdx.x;
    const int w    = tid >> 6;             // wave 0..7
    const int lane = tid & 63;
    const int otile = blockIdx.x;          // 0..511
    const int o0   = otile * 16;
    const int phase = (otile * 3) & (MSTEPS - 1);   // decorrelate k across blocks

    const int fmt = sniff_fmt(wn);

    // ---- LDS: 73 KB -> 2 blocks/CU ----
    __shared__ int   w_lds[2][8192];       // 2 x 32KB: [16 rows][2KB]
    __shared__ float nlds[NBLOCKS];        // 1KB
    __shared__ float red[8][256];          // 8KB

    if (tid < NBLOCKS)
        nlds[tid] = decode_norm(wn, otile * NBLOCKS + tid, fmt);

    // ---- staging geometry: wave w stages rows {2w, 2w+1}, 2 KB each, as
    //      4 x 1KB gload_lds. Source unit pre-swizzled (l ^ (row&7)) within
    //      128B groups; LDS dest linear. ----
    const int rA = 2 * w, rB = 2 * w + 1;
    const int uA = lane ^ (rA & 7);
    const int uB = lane ^ (rB & 7);
    // int32 base pointers (per instr): + Sp*512 per mega-step
    const int* gw0 = wq + (size_t)(o0 + rA) * ROW_I32 +       uA * 4;   // row A, KB 0
    const int* gw1 = wq + (size_t)(o0 + rA) * ROW_I32 + 256 + uA * 4;   // row A, KB 1
    const int* gw2 = wq + (size_t)(o0 + rB) * ROW_I32 +       uB * 4;   // row B, KB 0
    const int* gw3 = wq + (size_t)(o0 + rB) * ROW_I32 + 256 + uB * 4;   // row B, KB 1
    const int ldA0 = rA * 512;             // int32 index of row A KB0 in a buffer
    const int ldA1 = rA * 512 + 256;
    const int ldB0 = rB * 512;
    const int ldB1 = rB * 512 + 256;

    // ---- consume geometry: wave w owns k-blocks {4w..4w+3} of each mega-step.
    //      pv byte offset = col*2048 + ((w*16 + j*4 + kg) ^ (col&7)) * 16  ----
    const int col = lane & 15;
    const int kg  = lane >> 4;
    int cvoff[4];
    #pragma unroll
    for (int j = 0; j < 4; ++j)
        cvoff[j] = col * 2048 + (((w * 16 + j * 4 + kg) ^ (col & 7)) << 4);
    const short* xrow = xb + (size_t)col * I_TOTAL + kg * 8;

    f32x4 acc = {0.f, 0.f, 0.f, 0.f};

    // ---- prologue: stage mega-step `phase` into buf 0 ----
    {
        const size_t off = (size_t)phase * 512;
        __builtin_amdgcn_global_load_lds((GASV*)(gw0 + off), (LASV*)(&w_lds[0][ldA0]), 16, 0, 0);
        __builtin_amdgcn_global_load_lds((GASV*)(gw1 + off), (LASV*)(&w_lds[0][ldA1]), 16, 0, 0);
        __builtin_amdgcn_global_load_lds((GASV*)(gw2 + off), (LASV*)(&w_lds[0][ldB0]), 16, 0, 0);
        __builtin_amdgcn_global_load_lds((GASV*)(gw3 + off), (LASV*)(&w_lds[0][ldB1]), 16, 0, 0);
    }
    __syncthreads();   // buf0 + nlds ready

    for (int S = 0; S < MSTEPS; ++S) {
        const int cur = S & 1;
        const int Sp  = (S + phase) & (MSTEPS - 1);

        // stage S+1 into the other buffer (2 KB/row contiguous continuation)
        if (S + 1 < MSTEPS) {
            const int Spn = (S + 1 + phase) & (MSTEPS - 1);
            const size_t off = (size_t)Spn * 512;
            const int nxt = cur ^ 1;
            __builtin_amdgcn_global_load_lds((GASV*)(gw0 + off), (LASV*)(&w_lds[nxt][ldA0]), 16, 0, 0);
            __builtin_amdgcn_global_load_lds((GASV*)(gw1 + off), (LASV*)(&w_lds[nxt][ldA1]), 16, 0, 0);
            __builtin_amdgcn_global_load_lds((GASV*)(gw2 + off), (LASV*)(&w_lds[nxt][ldB0]), 16, 0, 0);
            __builtin_amdgcn_global_load_lds((GASV*)(gw3 + off), (LASV*)(&w_lds[nxt][ldB1]), 16, 0, 0);
        }

        // x for this mega-step's 4 k-blocks (L2-resident, to registers)
        const int kb0 = Sp * 32 + w * 4;
        bf16x8 xa0 = *(const bf16x8*)(xrow + (size_t)(kb0 + 0) * 32);
        bf16x8 xa1 = *(const bf16x8*)(xrow + (size_t)(kb0 + 1) * 32);
        bf16x8 xa2 = *(const bf16x8*)(xrow + (size_t)(kb0 + 2) * 32);
        bf16x8 xa3 = *(const bf16x8*)(xrow + (size_t)(kb0 + 3) * 32);

        const char* wb = (const char*)&w_lds[cur][0];

        #pragma unroll
        for (int j = 0; j < 4; ++j) {
            i32x4 pv = *(const i32x4*)(wb + cvoff[j]);
            const float nf = nlds[kb0 + j];
            const float sc = nf * (2.0f / 15.0f);
            bf16x8 bfrag;
            #pragma unroll
            for (int c = 0; c < 4; ++c) {
                int v = pv[c];
                bfrag[2*c]   = f2bf((float)(v & 15)        * sc - nf);
                bfrag[2*c+1] = f2bf((float)((v >> 4) & 15) * sc - nf);
            }
            bf16x8 xa = (j == 0) ? xa0 : (j == 1) ? xa1 : (j == 2) ? xa2 : xa3;
            acc = __builtin_amdgcn_mfma_f32_16x16x32_bf16(xa, bfrag, acc, 0, 0, 0);
        }

        __syncthreads();   // reads of buf cur done; stage S+1 landed
    }

    // ---- cross-wave K reduction ----
    *(f32x4*)&red[w][lane * 4] = acc;
    __syncthreads();

    if (tid < 256) {
        float s = 0.f;
        #pragma unroll
        for (int q = 0; q < 8; ++q) s += red[q][tid];
        const int l = tid >> 2;
        const int r = tid & 3;
        const int m  = ((l >> 4) << 2) + r;    // C row = (lane>>4)*4 + reg
        const int oc = o0 + (l & 15);          // C col = lane&15
        out[(size_t)m * O_TOTAL + oc] = s + bias[oc];
    }
}

extern "C" void kernel_launch(void* const* d_in, const int* in_sizes, int n_in,
                              void* d_out, int out_size, void* d_ws, size_t ws_size,
                              hipStream_t stream) {
    const float* x    = (const float*)d_in[0];
    const int*   wq   = (const int*)d_in[1];
    const void*  wn   = (const void*)d_in[2];
    const float* bias = (const float*)d_in[3];
    float* out = (float*)d_out;
    short* xb  = (short*)d_ws;                  // 256 KB scratch

    hipLaunchKernelGGL(xcvt_kernel, dim3(16 * I_TOTAL / 4 / 256), dim3(256), 0, stream, x, xb);

    hipLaunchKernelGGL(gemm_mb, dim3(O_TOTAL / 16), dim3(512), 0, stream,
                       (const short*)xb, wq, wn, bias, out);
}